// Round 9
// baseline (4076.737 us; speedup 1.0000x reference)
//
#include <hip/hip_runtime.h>
#include <stdint.h>

typedef __attribute__((ext_vector_type(8))) short bf16x8;
typedef __attribute__((ext_vector_type(4))) float f32x4;

#define T_TOTAL 32
#define BATCH   1024
#define INDIM   784
#define HDIM    4096
#define OUTDIM  10
#define BH      (BATCH * HDIM)      // 4,194,304
#define WORDS_PER_T (BH / 64)       // 65,536 u64 words per timestep
#define TC      8                   // timesteps per GEMM chunk
#define MC      (TC * BATCH)        // 8192 rows per chunk
// concat-K layout: 5 correction segments first (small magnitude), hh LAST.
// [0,784)=mm [784,1568)=hm [1568,2352)=mh [2352,3136)=hl [3136,3920)=lh
// [3920,3968)=0 [3968,4752)=hh [4752,4800)=0
#define KP      4800                // 75 * 64
#define DELTA   2e-3f               // near-threshold flag window

// ---------- exact 3-way bf16 truncation split: a == h + m + l ----------
__device__ __forceinline__ void split3(float a, ushort& h, ushort& m, ushort& l) {
    unsigned ua = __float_as_uint(a);
    h = (ushort)(ua >> 16);
    float r = a - __uint_as_float(ua & 0xFFFF0000u);   // exact
    unsigned ur = __float_as_uint(r);
    m = (ushort)(ur >> 16);
    float r2 = r - __uint_as_float(ur & 0xFFFF0000u);  // exact
    l = (ushort)(__float_as_uint(r2) >> 16);
}

// ---------- split fp32 [R][784] into concat-K bf16 [R][4800] ----------
__global__ __launch_bounds__(256) void k_split3(const float* __restrict__ src,
                                                ushort* __restrict__ dst,
                                                int R, int isA) {
    int idx = blockIdx.x * 256 + threadIdx.x;
    int main_n = R * 392;                       // 784/2 pairs per row
    if (idx < main_n) {
        int row = idx / 392, kk = (idx % 392) * 2;
        float a0 = src[(size_t)row * INDIM + kk];
        float a1 = src[(size_t)row * INDIM + kk + 1];
        ushort h0, m0, l0, h1, m1, l1;
        split3(a0, h0, m0, l0);
        split3(a1, h1, m1, l1);
        ushort2 H; H.x = h0; H.y = h1;
        ushort2 M; M.x = m0; M.y = m1;
        ushort2 L; L.x = l0; L.y = l1;
        ushort2 c1 = isA ? H : M;
        ushort2 c2 = isA ? M : H;
        ushort2 c3 = isA ? H : L;
        ushort2 c4 = isA ? L : H;
        ushort* d = dst + (size_t)row * KP;
        *(ushort2*)(d + kk)        = M;   // mm
        *(ushort2*)(d + 784 + kk)  = c1;  // hm
        *(ushort2*)(d + 1568 + kk) = c2;  // mh
        *(ushort2*)(d + 2352 + kk) = c3;  // hl
        *(ushort2*)(d + 3136 + kk) = c4;  // lh
        *(ushort2*)(d + 3968 + kk) = H;   // hh (last)
    } else if (idx < main_n + R * 48) {
        int j = idx - main_n;
        int row = j / 48, q = j % 48;
        int c = (q < 24) ? (3920 + q * 2) : (4752 + (q - 24) * 2);
        ushort2 z; z.x = 0; z.y = 0;
        *(ushort2*)(dst + (size_t)row * KP + c) = z;
    }
}

// ---------- W2 transpose: W2[10][4096] -> W2T[4096][10] ----------
__global__ void k_transpose_w2(const float* __restrict__ W2, float* __restrict__ W2T) {
    int i = blockIdx.x * 256 + threadIdx.x;
    if (i < HDIM * OUTDIM) {
        int h = i / OUTDIM, o = i % OUTDIM;
        W2T[i] = W2[o * HDIM + h];
    }
}

// ---------- bf16 MFMA GEMM (m97 structure): Z[m][n] = A'[m][:] . B'[n][:] ----------
// 128x128 tile, BK=64, 4 waves, 4x4 frags of 16x16x32. Verified launching (r2/r3).
__global__ __launch_bounds__(256) void k_gemm_bf16(const ushort* __restrict__ Ap,
                                                   const ushort* __restrict__ Bp,
                                                   float* __restrict__ Z) {
    __shared__ ushort Asm[128 * 64];   // [m][k] 16 KB
    __shared__ ushort Bsm[128 * 64];   // [n][k] 16 KB

    const int nwg = gridDim.x;
    const int cpx = nwg >> 3;
    const int bid = blockIdx.x;
    const int swz = (bid & 7) * cpx + (bid >> 3);
    const int bm = swz >> 5;           // 32 n-blocks (4096/128)
    const int bn = swz & 31;

    const int tid  = threadIdx.x;
    const int w    = tid >> 6, lane = tid & 63;
    const int wr   = w >> 1,   wc   = w & 1;
    const int fr   = lane & 15, fq  = lane >> 4;

    const ushort* agbase = Ap + ((size_t)(bm * 128 + w * 32 + (lane >> 3))) * KP + (lane & 7) * 8;
    const ushort* bgbase = Bp + ((size_t)(bn * 128 + w * 32 + (lane >> 3))) * KP + (lane & 7) * 8;
    ushort* alds = &Asm[(w * 32) * 64];
    ushort* blds = &Bsm[(w * 32) * 64];

    f32x4 acc[4][4];
#pragma unroll
    for (int i = 0; i < 4; ++i)
#pragma unroll
        for (int j = 0; j < 4; ++j) acc[i][j] = (f32x4){0.f, 0.f, 0.f, 0.f};

    const bf16x8* As8 = (const bf16x8*)Asm;
    const bf16x8* Bs8 = (const bf16x8*)Bsm;
    const int aoff = (wr * 64 + fr) * 8 + fq;
    const int boff = (wc * 64 + fr) * 8 + fq;

    for (int k0 = 0; k0 < KP; k0 += 64) {
#pragma unroll
        for (int i = 0; i < 4; ++i) {
            __builtin_amdgcn_global_load_lds(
                (const __attribute__((address_space(1))) void*)(agbase + (size_t)i * 8 * KP + k0),
                (__attribute__((address_space(3))) void*)(alds + i * 8 * 64), 16, 0, 0);
            __builtin_amdgcn_global_load_lds(
                (const __attribute__((address_space(1))) void*)(bgbase + (size_t)i * 8 * KP + k0),
                (__attribute__((address_space(3))) void*)(blds + i * 8 * 64), 16, 0, 0);
        }
        __syncthreads();
#pragma unroll
        for (int kk = 0; kk < 2; ++kk) {
            bf16x8 a0 = As8[aoff + kk * 4 + 0 * 128];
            bf16x8 a1 = As8[aoff + kk * 4 + 1 * 128];
            bf16x8 a2 = As8[aoff + kk * 4 + 2 * 128];
            bf16x8 a3 = As8[aoff + kk * 4 + 3 * 128];
            bf16x8 b0 = Bs8[boff + kk * 4 + 0 * 128];
            bf16x8 b1 = Bs8[boff + kk * 4 + 1 * 128];
            bf16x8 b2 = Bs8[boff + kk * 4 + 2 * 128];
            bf16x8 b3 = Bs8[boff + kk * 4 + 3 * 128];
            acc[0][0] = __builtin_amdgcn_mfma_f32_16x16x32_bf16(a0, b0, acc[0][0], 0, 0, 0);
            acc[0][1] = __builtin_amdgcn_mfma_f32_16x16x32_bf16(a0, b1, acc[0][1], 0, 0, 0);
            acc[0][2] = __builtin_amdgcn_mfma_f32_16x16x32_bf16(a0, b2, acc[0][2], 0, 0, 0);
            acc[0][3] = __builtin_amdgcn_mfma_f32_16x16x32_bf16(a0, b3, acc[0][3], 0, 0, 0);
            acc[1][0] = __builtin_amdgcn_mfma_f32_16x16x32_bf16(a1, b0, acc[1][0], 0, 0, 0);
            acc[1][1] = __builtin_amdgcn_mfma_f32_16x16x32_bf16(a1, b1, acc[1][1], 0, 0, 0);
            acc[1][2] = __builtin_amdgcn_mfma_f32_16x16x32_bf16(a1, b2, acc[1][2], 0, 0, 0);
            acc[1][3] = __builtin_amdgcn_mfma_f32_16x16x32_bf16(a1, b3, acc[1][3], 0, 0, 0);
            acc[2][0] = __builtin_amdgcn_mfma_f32_16x16x32_bf16(a2, b0, acc[2][0], 0, 0, 0);
            acc[2][1] = __builtin_amdgcn_mfma_f32_16x16x32_bf16(a2, b1, acc[2][1], 0, 0, 0);
            acc[2][2] = __builtin_amdgcn_mfma_f32_16x16x32_bf16(a2, b2, acc[2][2], 0, 0, 0);
            acc[2][3] = __builtin_amdgcn_mfma_f32_16x16x32_bf16(a2, b3, acc[2][3], 0, 0, 0);
            acc[3][0] = __builtin_amdgcn_mfma_f32_16x16x32_bf16(a3, b0, acc[3][0], 0, 0, 0);
            acc[3][1] = __builtin_amdgcn_mfma_f32_16x16x32_bf16(a3, b1, acc[3][1], 0, 0, 0);
            acc[3][2] = __builtin_amdgcn_mfma_f32_16x16x32_bf16(a3, b2, acc[3][2], 0, 0, 0);
            acc[3][3] = __builtin_amdgcn_mfma_f32_16x16x32_bf16(a3, b3, acc[3][3], 0, 0, 0);
        }
        __syncthreads();
    }

    // C/D layout (m89-verified): col = lane&15, row = (lane>>4)*4 + reg
    const int mbase = bm * 128 + wr * 64 + fq * 4;
    const int nbase = bn * 128 + wc * 64 + fr;
#pragma unroll
    for (int i = 0; i < 4; ++i)
#pragma unroll
        for (int j = 0; j < 4; ++j)
#pragma unroll
            for (int r = 0; r < 4; ++r)
                Z[(size_t)(mbase + i * 16 + r) * HDIM + nbase + j * 16] = acc[i][j][r];
}

// ---------- Layer-1 approx IF recurrence + near-threshold flagging ----------
// v chain on approx z; spike bits -> S1; |v-1|<DELTA at any t -> flag the pair.
// Sound: if never within DELTA and |v_approx - v_exact| < DELTA (<=32 z-errors,
// each ~1e-5 << DELTA), every spike decision matches the exact chain.
__global__ __launch_bounds__(256) void k_layer1_flag(const float* __restrict__ Z,
                                                     float* __restrict__ v1s,
                                                     uint64_t* __restrict__ S1,
                                                     uint64_t* __restrict__ flags,
                                                     int tbase, int first) {
    const size_t i = (size_t)blockIdx.x * 256 + threadIdx.x;
    float v = first ? 0.0f : v1s[i];
    const int lane = threadIdx.x & 63;
    const size_t word = i >> 6;
    uint64_t nearAcc = 0;
    for (int t = 0; t < TC; ++t) {
        v += Z[(size_t)t * BH + i];
        bool s    = (v >= 1.0f);
        bool near = (fabsf(v - 1.0f) < DELTA);
        unsigned long long sm = __ballot(s);
        nearAcc |= (uint64_t)__ballot(near);
        if (lane == 0) S1[(size_t)(tbase + t) * WORDS_PER_T + word] = sm;
        if (s) v = 0.0f;
    }
    if (lane == 0) flags[word] = first ? nearAcc : (flags[word] | nearAcc);
    v1s[i] = v;
}

// ---------- Exact fixup: recompute flagged (b,h) chains bitwise (ascending-k fp32 fma) ----------
// One block per b. Flagged h's listed in LDS; x[t,b,:] staged in LDS per t;
// each thread runs the exact serial chain for one h and force-writes S1 bits.
__global__ __launch_bounds__(256) void k_fixup(const float* __restrict__ x,
                                               const float* __restrict__ W1,
                                               const uint64_t* __restrict__ flags,
                                               uint64_t* __restrict__ S1) {
    __shared__ float xs[INDIM];
    __shared__ int   list[4096];
    __shared__ int   cnt;
    const int b   = blockIdx.x;
    const int tid = threadIdx.x;
    if (tid == 0) cnt = 0;
    __syncthreads();
    if (tid < 64) {
        uint64_t w = flags[b * 64 + tid];
        while (w) {
            int bit = __builtin_ctzll(w);
            w &= w - 1;
            int p = atomicAdd(&cnt, 1);
            list[p] = tid * 64 + bit;
        }
    }
    __syncthreads();
    const int n = cnt;
    if (n == 0) return;
    for (int j0 = 0; j0 < n; j0 += 256) {
        const int j = j0 + tid;
        const int h = (j < n) ? list[j] : -1;
        float v = 0.0f;
        for (int t = 0; t < T_TOTAL; ++t) {
            __syncthreads();   // previous iteration done with xs
            for (int k = tid; k < INDIM; k += 256)
                xs[k] = x[((size_t)t * BATCH + b) * INDIM + k];
            __syncthreads();
            if (h >= 0) {
                const float* wr = W1 + (size_t)h * INDIM;
                float z = 0.0f;
#pragma unroll 8
                for (int k = 0; k < INDIM; ++k) z = fmaf(xs[k], wr[k], z);
                v += z;
                bool s = (v >= 1.0f);
                unsigned long long* wp =
                    (unsigned long long*)&S1[(size_t)t * WORDS_PER_T + (size_t)b * 64 + (h >> 6)];
                unsigned long long m = 1ull << (h & 63);
                if (s) { atomicOr(wp, m); v = 0.0f; }
                else   { atomicAnd(wp, ~m); }
            }
        }
    }
}

// ---------- Layer-2 partial sums from spike bitmask ----------
__global__ __launch_bounds__(256) void k_layer2_partial(const uint64_t* __restrict__ S1,
                                                        const float* __restrict__ W2T,
                                                        float* __restrict__ part,
                                                        int rowsTotal) {
    __shared__ float w[1024][10];   // 40 KB
    const int hs = blockIdx.y;
    for (int i = threadIdx.x; i < 1024 * 10; i += 256)
        w[i / 10][i % 10] = W2T[hs * 1024 * 10 + i];
    __syncthreads();

    const int row = blockIdx.x * 256 + threadIdx.x;
    const uint64_t* wp = S1 + (size_t)row * 64 + hs * 16;
    float acc[10] = {};
    for (int wi = 0; wi < 16; ++wi) {
        uint64_t m = wp[wi];
        while (m) {
            int bit = __builtin_ctzll(m);
            m &= m - 1;
            int hl = wi * 64 + bit;
#pragma unroll
            for (int o = 0; o < 10; ++o) acc[o] += w[hl][o];
        }
    }
    float* p = part + ((size_t)hs * rowsTotal + row) * 10;
#pragma unroll
    for (int o = 0; o < 10; ++o) p[o] = acc[o];
}

// ---------- Layer-2 IF recurrence + spike record (all 32 t, one launch) ----------
__global__ __launch_bounds__(256) void k_layer2_rec(const float* __restrict__ part,
                                                    float* __restrict__ out) {
    const int i = blockIdx.x * 256 + threadIdx.x;
    if (i >= BATCH * OUTDIM) return;
    float v = 0.0f, rec = 0.0f;
    const int rowsTotal = T_TOTAL * BATCH;
    const int b = i / OUTDIM, o = i % OUTDIM;
    for (int t = 0; t < T_TOTAL; ++t) {
        const int r = t * BATCH + b;
        float sig = 0.0f;
#pragma unroll
        for (int hs = 0; hs < 4; ++hs)
            sig += part[((size_t)hs * rowsTotal + r) * 10 + o];
        v += sig;
        bool s = (v >= 1.0f);
        rec += s ? 1.0f : 0.0f;
        if (s) v = 0.0f;
    }
    out[i] = rec;
}

// ---------- launch ----------
extern "C" void kernel_launch(void* const* d_in, const int* in_sizes, int n_in,
                              void* d_out, int out_size, void* d_ws, size_t ws_size,
                              hipStream_t stream) {
    (void)in_sizes; (void)n_in; (void)out_size; (void)ws_size;
    const float* x  = (const float*)d_in[0];   // [32][1024][784]
    const float* W1 = (const float*)d_in[1];   // [4096][784]
    const float* W2 = (const float*)d_in[2];   // [10][4096]
    float* out = (float*)d_out;                // [1024][10]

    // ws layout (total ~292 MB; ws >= ~296 MB established by earlier rounds)
    char* p = (char*)d_ws;
    float*    W2T   = (float*)p;    p += (size_t)HDIM * OUTDIM * 4;        // 160 KB
    float*    v1s   = (float*)p;    p += (size_t)BH * 4;                   // 16.8 MB
    ushort*   Bp    = (ushort*)p;   p += (size_t)HDIM * KP * 2;            // 39.3 MB
    ushort*   Ap    = (ushort*)p;   p += (size_t)MC * KP * 2;              // 78.6 MB
    float*    Z     = (float*)p;    p += (size_t)TC * BH * 4;              // 134.2 MB
    uint64_t* S1    = (uint64_t*)p; p += (size_t)T_TOTAL * WORDS_PER_T * 8;// 16.8 MB
    uint64_t* flags = (uint64_t*)p; p += (size_t)WORDS_PER_T * 8;          // 0.5 MB
    float*    part  = (float*)p;                                           // 5.2 MB

    k_transpose_w2<<<(HDIM * OUTDIM + 255) / 256, 256, 0, stream>>>(W2, W2T);
    k_split3<<<(HDIM * 440 + 255) / 256, 256, 0, stream>>>(W1, Bp, HDIM, 0);

    const int nch = T_TOTAL / TC;   // 4
    for (int c = 0; c < nch; ++c) {
        const float* xc = x + (size_t)c * MC * INDIM;
        k_split3<<<(MC * 440 + 255) / 256, 256, 0, stream>>>(xc, Ap, MC, 1);
        k_gemm_bf16<<<(MC / 128) * 32, 256, 0, stream>>>(Ap, Bp, Z);
        k_layer1_flag<<<BH / 256, 256, 0, stream>>>(Z, v1s, S1, flags, c * TC, c == 0);
    }
    k_fixup<<<BATCH, 256, 0, stream>>>(x, W1, flags, S1);
    k_layer2_partial<<<dim3(T_TOTAL * BATCH / 256, 4), 256, 0, stream>>>(
        S1, W2T, part, T_TOTAL * BATCH);
    k_layer2_rec<<<(BATCH * OUTDIM + 255) / 256, 256, 0, stream>>>(part, out);
}

// Round 10
// 1789.044 us; speedup vs baseline: 2.2787x; 2.2787x over previous
//
#include <hip/hip_runtime.h>
#include <stdint.h>

typedef __attribute__((ext_vector_type(8))) short bf16x8;
typedef __attribute__((ext_vector_type(4))) float f32x4;

#define T_TOTAL 32
#define BATCH   1024
#define INDIM   784
#define HDIM    4096
#define OUTDIM  10
#define BH      (BATCH * HDIM)      // 4,194,304
#define WORDS_PER_T (BH / 64)       // 65,536 u64 words per timestep
#define TC      8                   // timesteps per GEMM chunk
#define MC      (TC * BATCH)        // 8192 rows per chunk
// concat-K layout (small-magnitude segments first, hh LAST):
// [0,784)=mm [784,1568)=hm [1568,2352)=mh [2352,3136)=hh [3136,3200)=0
#define KP      3200                // 50 * 64
#define DELTA   2e-3f               // near-threshold flag window (proven r9)
#define FIXLIST 3072

// ---------- 2-way bf16 truncation split: a = h + m + residual(~2^-16) ----------
__device__ __forceinline__ void split2(float a, ushort& h, ushort& m) {
    unsigned ua = __float_as_uint(a);
    h = (ushort)(ua >> 16);
    float r = a - __uint_as_float(ua & 0xFFFF0000u);   // exact
    m = (ushort)(__float_as_uint(r) >> 16);
}

// ---------- split fp32 [R][784] into concat-K bf16 [R][3200] ----------
__global__ __launch_bounds__(256) void k_split3(const float* __restrict__ src,
                                                ushort* __restrict__ dst,
                                                int R, int isA) {
    int idx = blockIdx.x * 256 + threadIdx.x;
    int main_n = R * 392;                       // 784/2 pairs per row
    if (idx < main_n) {
        int row = idx / 392, kk = (idx % 392) * 2;
        float a0 = src[(size_t)row * INDIM + kk];
        float a1 = src[(size_t)row * INDIM + kk + 1];
        ushort h0, m0, h1, m1;
        split2(a0, h0, m0);
        split2(a1, h1, m1);
        ushort2 H; H.x = h0; H.y = h1;
        ushort2 M; M.x = m0; M.y = m1;
        ushort2 s1 = isA ? H : M;   // hm: A=h, B=m
        ushort2 s2 = isA ? M : H;   // mh: A=m, B=h
        ushort* d = dst + (size_t)row * KP;
        *(ushort2*)(d + kk)        = M;   // mm
        *(ushort2*)(d + 784 + kk)  = s1;  // hm
        *(ushort2*)(d + 1568 + kk) = s2;  // mh
        *(ushort2*)(d + 2352 + kk) = H;   // hh (accumulated last)
    } else if (idx < main_n + R * 32) {
        int j = idx - main_n;
        int row = j / 32, q = j % 32;
        ushort2 z; z.x = 0; z.y = 0;
        *(ushort2*)(dst + (size_t)row * KP + 3136 + q * 2) = z;
    }
}

// ---------- W2 transpose: W2[10][4096] -> W2T[4096][10] ----------
__global__ void k_transpose_w2(const float* __restrict__ W2, float* __restrict__ W2T) {
    int i = blockIdx.x * 256 + threadIdx.x;
    if (i < HDIM * OUTDIM) {
        int h = i / OUTDIM, o = i % OUTDIM;
        W2T[i] = W2[o * HDIM + h];
    }
}

// ---------- bf16 MFMA GEMM (m97 structure): Z[m][n] = A'[m][:] . B'[n][:] ----------
// 128x128 tile, BK=64, 4 waves, 4x4 frags of 16x16x32. (passed r9, only KP changed)
__global__ __launch_bounds__(256) void k_gemm_bf16(const ushort* __restrict__ Ap,
                                                   const ushort* __restrict__ Bp,
                                                   float* __restrict__ Z) {
    __shared__ ushort Asm[128 * 64];   // [m][k] 16 KB
    __shared__ ushort Bsm[128 * 64];   // [n][k] 16 KB

    const int nwg = gridDim.x;
    const int cpx = nwg >> 3;
    const int bid = blockIdx.x;
    const int swz = (bid & 7) * cpx + (bid >> 3);
    const int bm = swz >> 5;           // 32 n-blocks (4096/128)
    const int bn = swz & 31;

    const int tid  = threadIdx.x;
    const int w    = tid >> 6, lane = tid & 63;
    const int wr   = w >> 1,   wc   = w & 1;
    const int fr   = lane & 15, fq  = lane >> 4;

    const ushort* agbase = Ap + ((size_t)(bm * 128 + w * 32 + (lane >> 3))) * KP + (lane & 7) * 8;
    const ushort* bgbase = Bp + ((size_t)(bn * 128 + w * 32 + (lane >> 3))) * KP + (lane & 7) * 8;
    ushort* alds = &Asm[(w * 32) * 64];
    ushort* blds = &Bsm[(w * 32) * 64];

    f32x4 acc[4][4];
#pragma unroll
    for (int i = 0; i < 4; ++i)
#pragma unroll
        for (int j = 0; j < 4; ++j) acc[i][j] = (f32x4){0.f, 0.f, 0.f, 0.f};

    const bf16x8* As8 = (const bf16x8*)Asm;
    const bf16x8* Bs8 = (const bf16x8*)Bsm;
    const int aoff = (wr * 64 + fr) * 8 + fq;
    const int boff = (wc * 64 + fr) * 8 + fq;

    for (int k0 = 0; k0 < KP; k0 += 64) {
#pragma unroll
        for (int i = 0; i < 4; ++i) {
            __builtin_amdgcn_global_load_lds(
                (const __attribute__((address_space(1))) void*)(agbase + (size_t)i * 8 * KP + k0),
                (__attribute__((address_space(3))) void*)(alds + i * 8 * 64), 16, 0, 0);
            __builtin_amdgcn_global_load_lds(
                (const __attribute__((address_space(1))) void*)(bgbase + (size_t)i * 8 * KP + k0),
                (__attribute__((address_space(3))) void*)(blds + i * 8 * 64), 16, 0, 0);
        }
        __syncthreads();
#pragma unroll
        for (int kk = 0; kk < 2; ++kk) {
            bf16x8 a0 = As8[aoff + kk * 4 + 0 * 128];
            bf16x8 a1 = As8[aoff + kk * 4 + 1 * 128];
            bf16x8 a2 = As8[aoff + kk * 4 + 2 * 128];
            bf16x8 a3 = As8[aoff + kk * 4 + 3 * 128];
            bf16x8 b0 = Bs8[boff + kk * 4 + 0 * 128];
            bf16x8 b1 = Bs8[boff + kk * 4 + 1 * 128];
            bf16x8 b2 = Bs8[boff + kk * 4 + 2 * 128];
            bf16x8 b3 = Bs8[boff + kk * 4 + 3 * 128];
            acc[0][0] = __builtin_amdgcn_mfma_f32_16x16x32_bf16(a0, b0, acc[0][0], 0, 0, 0);
            acc[0][1] = __builtin_amdgcn_mfma_f32_16x16x32_bf16(a0, b1, acc[0][1], 0, 0, 0);
            acc[0][2] = __builtin_amdgcn_mfma_f32_16x16x32_bf16(a0, b2, acc[0][2], 0, 0, 0);
            acc[0][3] = __builtin_amdgcn_mfma_f32_16x16x32_bf16(a0, b3, acc[0][3], 0, 0, 0);
            acc[1][0] = __builtin_amdgcn_mfma_f32_16x16x32_bf16(a1, b0, acc[1][0], 0, 0, 0);
            acc[1][1] = __builtin_amdgcn_mfma_f32_16x16x32_bf16(a1, b1, acc[1][1], 0, 0, 0);
            acc[1][2] = __builtin_amdgcn_mfma_f32_16x16x32_bf16(a1, b2, acc[1][2], 0, 0, 0);
            acc[1][3] = __builtin_amdgcn_mfma_f32_16x16x32_bf16(a1, b3, acc[1][3], 0, 0, 0);
            acc[2][0] = __builtin_amdgcn_mfma_f32_16x16x32_bf16(a2, b0, acc[2][0], 0, 0, 0);
            acc[2][1] = __builtin_amdgcn_mfma_f32_16x16x32_bf16(a2, b1, acc[2][1], 0, 0, 0);
            acc[2][2] = __builtin_amdgcn_mfma_f32_16x16x32_bf16(a2, b2, acc[2][2], 0, 0, 0);
            acc[2][3] = __builtin_amdgcn_mfma_f32_16x16x32_bf16(a2, b3, acc[2][3], 0, 0, 0);
            acc[3][0] = __builtin_amdgcn_mfma_f32_16x16x32_bf16(a3, b0, acc[3][0], 0, 0, 0);
            acc[3][1] = __builtin_amdgcn_mfma_f32_16x16x32_bf16(a3, b1, acc[3][1], 0, 0, 0);
            acc[3][2] = __builtin_amdgcn_mfma_f32_16x16x32_bf16(a3, b2, acc[3][2], 0, 0, 0);
            acc[3][3] = __builtin_amdgcn_mfma_f32_16x16x32_bf16(a3, b3, acc[3][3], 0, 0, 0);
        }
        __syncthreads();
    }

    // C/D layout (m89-verified): col = lane&15, row = (lane>>4)*4 + reg
    const int mbase = bm * 128 + wr * 64 + fq * 4;
    const int nbase = bn * 128 + wc * 64 + fr;
#pragma unroll
    for (int i = 0; i < 4; ++i)
#pragma unroll
        for (int j = 0; j < 4; ++j)
#pragma unroll
            for (int r = 0; r < 4; ++r)
                Z[(size_t)(mbase + i * 16 + r) * HDIM + nbase + j * 16] = acc[i][j][r];
}

// ---------- Layer-1 approx IF recurrence + near-threshold flagging ----------
__global__ __launch_bounds__(256) void k_layer1_flag(const float* __restrict__ Z,
                                                     float* __restrict__ v1s,
                                                     uint64_t* __restrict__ S1,
                                                     uint64_t* __restrict__ flags,
                                                     int tbase, int first) {
    const size_t i = (size_t)blockIdx.x * 256 + threadIdx.x;
    float v = first ? 0.0f : v1s[i];
    const int lane = threadIdx.x & 63;
    const size_t word = i >> 6;
    uint64_t nearAcc = 0;
    for (int t = 0; t < TC; ++t) {
        v += Z[(size_t)t * BH + i];
        bool s    = (v >= 1.0f);
        bool near = (fabsf(v - 1.0f) < DELTA);
        unsigned long long sm = __ballot(s);
        nearAcc |= (uint64_t)__ballot(near);
        if (lane == 0) S1[(size_t)(tbase + t) * WORDS_PER_T + word] = sm;
        if (s) v = 0.0f;
    }
    if (lane == 0) flags[word] = first ? nearAcc : (flags[word] | nearAcc);
    v1s[i] = v;
}

// ---------- Exact fixup: recompute flagged (b,h) chains bitwise ----------
// Block per b. x staged in LDS 16 timesteps at a time; each flagged-h thread
// makes ONE ascending-k pass over its W1 row (float4), updating 16 independent
// z[t] accumulators per k (16-way ILP; each z[t] chain is ascending-k fma ->
// bitwise identical to the reference). v carried across the two half-passes.
__global__ __launch_bounds__(256) void k_fixup(const float* __restrict__ x,
                                               const float* __restrict__ W1,
                                               const uint64_t* __restrict__ flags,
                                               uint64_t* __restrict__ S1) {
    __shared__ float xs[16][788];   // [t][k], rows 16B-aligned; 50.4 KB
    __shared__ int   list[FIXLIST];
    __shared__ int   cnt;
    const int b   = blockIdx.x;
    const int tid = threadIdx.x;
    if (tid == 0) cnt = 0;
    __syncthreads();
    if (tid < 64) {
        uint64_t w = flags[b * 64 + tid];
        while (w) {
            int bit = __builtin_ctzll(w);
            w &= w - 1;
            int p = atomicAdd(&cnt, 1);
            if (p < FIXLIST) list[p] = tid * 64 + bit;
        }
    }
    __syncthreads();
    const int n = min(cnt, FIXLIST);
    if (n == 0) return;

    for (int j0 = 0; j0 < n; j0 += 256) {
        const int j = j0 + tid;
        const int h = (j < n) ? list[j] : -1;
        const float* wrow = W1 + (size_t)(h >= 0 ? h : 0) * INDIM;
        float v = 0.0f;
        for (int half = 0; half < 2; ++half) {
            __syncthreads();   // previous pass done reading xs
            for (int idx = tid; idx < 16 * 196; idx += 256) {
                int t  = idx / 196;
                int kq = (idx % 196) * 4;
                float4 vx = *(const float4*)(x + ((size_t)(half * 16 + t) * BATCH + b) * INDIM + kq);
                *(float4*)&xs[t][kq] = vx;
            }
            __syncthreads();
            if (h >= 0) {
                float z[16];
#pragma unroll
                for (int t = 0; t < 16; ++t) z[t] = 0.0f;
                for (int kq = 0; kq < INDIM; kq += 4) {
                    float4 w4 = *(const float4*)(wrow + kq);
#pragma unroll
                    for (int t = 0; t < 16; ++t) {
                        float4 xv = *(const float4*)&xs[t][kq];   // wave-broadcast reads
                        z[t] = fmaf(xv.x, w4.x, z[t]);
                        z[t] = fmaf(xv.y, w4.y, z[t]);
                        z[t] = fmaf(xv.z, w4.z, z[t]);
                        z[t] = fmaf(xv.w, w4.w, z[t]);
                    }
                }
#pragma unroll
                for (int t = 0; t < 16; ++t) {
                    v += z[t];
                    bool s = (v >= 1.0f);
                    unsigned long long* wp = (unsigned long long*)
                        &S1[(size_t)(half * 16 + t) * WORDS_PER_T + (size_t)b * 64 + (h >> 6)];
                    unsigned long long m = 1ull << (h & 63);
                    if (s) { atomicOr(wp, m); v = 0.0f; }
                    else   { atomicAnd(wp, ~m); }
                }
            }
        }
    }
}

// ---------- Layer-2 partial sums from spike bitmask ----------
__global__ __launch_bounds__(256) void k_layer2_partial(const uint64_t* __restrict__ S1,
                                                        const float* __restrict__ W2T,
                                                        float* __restrict__ part,
                                                        int rowsTotal) {
    __shared__ float w[1024][10];   // 40 KB
    const int hs = blockIdx.y;
    for (int i = threadIdx.x; i < 1024 * 10; i += 256)
        w[i / 10][i % 10] = W2T[hs * 1024 * 10 + i];
    __syncthreads();

    const int row = blockIdx.x * 256 + threadIdx.x;
    const uint64_t* wp = S1 + (size_t)row * 64 + hs * 16;
    float acc[10] = {};
    for (int wi = 0; wi < 16; ++wi) {
        uint64_t m = wp[wi];
        while (m) {
            int bit = __builtin_ctzll(m);
            m &= m - 1;
            int hl = wi * 64 + bit;
#pragma unroll
            for (int o = 0; o < 10; ++o) acc[o] += w[hl][o];
        }
    }
    float* p = part + ((size_t)hs * rowsTotal + row) * 10;
#pragma unroll
    for (int o = 0; o < 10; ++o) p[o] = acc[o];
}

// ---------- Layer-2 IF recurrence + spike record ----------
__global__ __launch_bounds__(256) void k_layer2_rec(const float* __restrict__ part,
                                                    float* __restrict__ out) {
    const int i = blockIdx.x * 256 + threadIdx.x;
    if (i >= BATCH * OUTDIM) return;
    float v = 0.0f, rec = 0.0f;
    const int rowsTotal = T_TOTAL * BATCH;
    const int b = i / OUTDIM, o = i % OUTDIM;
    for (int t = 0; t < T_TOTAL; ++t) {
        const int r = t * BATCH + b;
        float sig = 0.0f;
#pragma unroll
        for (int hs = 0; hs < 4; ++hs)
            sig += part[((size_t)hs * rowsTotal + r) * 10 + o];
        v += sig;
        bool s = (v >= 1.0f);
        rec += s ? 1.0f : 0.0f;
        if (s) v = 0.0f;
    }
    out[i] = rec;
}

// ---------- launch ----------
extern "C" void kernel_launch(void* const* d_in, const int* in_sizes, int n_in,
                              void* d_out, int out_size, void* d_ws, size_t ws_size,
                              hipStream_t stream) {
    (void)in_sizes; (void)n_in; (void)out_size; (void)ws_size;
    const float* x  = (const float*)d_in[0];   // [32][1024][784]
    const float* W1 = (const float*)d_in[1];   // [4096][784]
    const float* W2 = (const float*)d_in[2];   // [10][4096]
    float* out = (float*)d_out;                // [1024][10]

    // ws layout (total ~252 MB)
    char* p = (char*)d_ws;
    float*    W2T   = (float*)p;    p += (size_t)HDIM * OUTDIM * 4;        // 160 KB
    float*    v1s   = (float*)p;    p += (size_t)BH * 4;                   // 16.8 MB
    ushort*   Bp    = (ushort*)p;   p += (size_t)HDIM * KP * 2;            // 26.2 MB
    ushort*   Ap    = (ushort*)p;   p += (size_t)MC * KP * 2;              // 52.4 MB
    float*    Z     = (float*)p;    p += (size_t)TC * BH * 4;              // 134.2 MB
    uint64_t* S1    = (uint64_t*)p; p += (size_t)T_TOTAL * WORDS_PER_T * 8;// 16.8 MB
    uint64_t* flags = (uint64_t*)p; p += (size_t)WORDS_PER_T * 8;          // 0.5 MB
    float*    part  = (float*)p;                                           // 5.2 MB

    k_transpose_w2<<<(HDIM * OUTDIM + 255) / 256, 256, 0, stream>>>(W2, W2T);
    k_split3<<<(HDIM * 424 + 255) / 256, 256, 0, stream>>>(W1, Bp, HDIM, 0);

    const int nch = T_TOTAL / TC;   // 4
    for (int c = 0; c < nch; ++c) {
        const float* xc = x + (size_t)c * MC * INDIM;
        k_split3<<<(MC * 424 + 255) / 256, 256, 0, stream>>>(xc, Ap, MC, 1);
        k_gemm_bf16<<<(MC / 128) * 32, 256, 0, stream>>>(Ap, Bp, Z);
        k_layer1_flag<<<BH / 256, 256, 0, stream>>>(Z, v1s, S1, flags, c * TC, c == 0);
    }
    k_fixup<<<BATCH, 256, 0, stream>>>(x, W1, flags, S1);
    k_layer2_partial<<<dim3(T_TOTAL * BATCH / 256, 4), 256, 0, stream>>>(
        S1, W2T, part, T_TOTAL * BATCH);
    k_layer2_rec<<<(BATCH * OUTDIM + 255) / 256, 256, 0, stream>>>(part, out);
}

// Round 11
// 1507.690 us; speedup vs baseline: 2.7040x; 1.1866x over previous
//
#include <hip/hip_runtime.h>
#include <stdint.h>

typedef __attribute__((ext_vector_type(8))) short bf16x8;
typedef __attribute__((ext_vector_type(4))) float f32x4;

#define T_TOTAL 32
#define BATCH   1024
#define INDIM   784
#define HDIM    4096
#define OUTDIM  10
#define BH      (BATCH * HDIM)      // 4,194,304
#define WORDS_PER_T (BH / 64)       // 65,536 u64 words per timestep
#define TC      8                   // timesteps per GEMM chunk
#define MC      (TC * BATCH)        // 8192 rows per chunk
// concat-K layout (small-magnitude segments first, hh LAST):
// [0,784)=hm [784,1568)=mh [1568,2352)=hh [2352,2368)=0
// dropped: mm + l-residual products (~2-3e-5 rms in v) -- covered by the
// DELTA flag window + exact fixup (r10 validated the same error class).
#define KP      2368                // 37 * 64
#define DELTA   2e-3f               // near-threshold flag window (proven r9/r10)
#define FIXLIST 3072

// ---------- 2-way bf16 truncation split: a = h + m + residual(~2^-16) ----------
__device__ __forceinline__ void split2(float a, ushort& h, ushort& m) {
    unsigned ua = __float_as_uint(a);
    h = (ushort)(ua >> 16);
    float r = a - __uint_as_float(ua & 0xFFFF0000u);   // exact
    m = (ushort)(__float_as_uint(r) >> 16);
}

// ---------- split fp32 [R][784] into concat-K bf16 [R][2368] ----------
__global__ __launch_bounds__(256) void k_split3(const float* __restrict__ src,
                                                ushort* __restrict__ dst,
                                                int R, int isA) {
    int idx = blockIdx.x * 256 + threadIdx.x;
    int main_n = R * 392;                       // 784/2 pairs per row
    if (idx < main_n) {
        int row = idx / 392, kk = (idx % 392) * 2;
        float a0 = src[(size_t)row * INDIM + kk];
        float a1 = src[(size_t)row * INDIM + kk + 1];
        ushort h0, m0, h1, m1;
        split2(a0, h0, m0);
        split2(a1, h1, m1);
        ushort2 H; H.x = h0; H.y = h1;
        ushort2 M; M.x = m0; M.y = m1;
        ushort2 s1 = isA ? H : M;   // hm: A=h, B=m
        ushort2 s2 = isA ? M : H;   // mh: A=m, B=h
        ushort* d = dst + (size_t)row * KP;
        *(ushort2*)(d + kk)        = s1;  // hm
        *(ushort2*)(d + 784 + kk)  = s2;  // mh
        *(ushort2*)(d + 1568 + kk) = H;   // hh (accumulated last)
    } else if (idx < main_n + R * 8) {
        int j = idx - main_n;
        int row = j / 8, q = j % 8;
        ushort2 z; z.x = 0; z.y = 0;
        *(ushort2*)(dst + (size_t)row * KP + 2352 + q * 2) = z;
    }
}

// ---------- W2 transpose: W2[10][4096] -> W2T[4096][10] ----------
__global__ void k_transpose_w2(const float* __restrict__ W2, float* __restrict__ W2T) {
    int i = blockIdx.x * 256 + threadIdx.x;
    if (i < HDIM * OUTDIM) {
        int h = i / OUTDIM, o = i % OUTDIM;
        W2T[i] = W2[o * HDIM + h];
    }
}

// ---------- bf16 MFMA GEMM (m97 structure): Z[m][n] = A'[m][:] . B'[n][:] ----------
// 128x128 tile, BK=64, 4 waves, 4x4 frags of 16x16x32. (passed r9/r10; only KP changed)
__global__ __launch_bounds__(256) void k_gemm_bf16(const ushort* __restrict__ Ap,
                                                   const ushort* __restrict__ Bp,
                                                   float* __restrict__ Z) {
    __shared__ ushort Asm[128 * 64];   // [m][k] 16 KB
    __shared__ ushort Bsm[128 * 64];   // [n][k] 16 KB

    const int nwg = gridDim.x;
    const int cpx = nwg >> 3;
    const int bid = blockIdx.x;
    const int swz = (bid & 7) * cpx + (bid >> 3);
    const int bm = swz >> 5;           // 32 n-blocks (4096/128)
    const int bn = swz & 31;

    const int tid  = threadIdx.x;
    const int w    = tid >> 6, lane = tid & 63;
    const int wr   = w >> 1,   wc   = w & 1;
    const int fr   = lane & 15, fq  = lane >> 4;

    const ushort* agbase = Ap + ((size_t)(bm * 128 + w * 32 + (lane >> 3))) * KP + (lane & 7) * 8;
    const ushort* bgbase = Bp + ((size_t)(bn * 128 + w * 32 + (lane >> 3))) * KP + (lane & 7) * 8;
    ushort* alds = &Asm[(w * 32) * 64];
    ushort* blds = &Bsm[(w * 32) * 64];

    f32x4 acc[4][4];
#pragma unroll
    for (int i = 0; i < 4; ++i)
#pragma unroll
        for (int j = 0; j < 4; ++j) acc[i][j] = (f32x4){0.f, 0.f, 0.f, 0.f};

    const bf16x8* As8 = (const bf16x8*)Asm;
    const bf16x8* Bs8 = (const bf16x8*)Bsm;
    const int aoff = (wr * 64 + fr) * 8 + fq;
    const int boff = (wc * 64 + fr) * 8 + fq;

    for (int k0 = 0; k0 < KP; k0 += 64) {
#pragma unroll
        for (int i = 0; i < 4; ++i) {
            __builtin_amdgcn_global_load_lds(
                (const __attribute__((address_space(1))) void*)(agbase + (size_t)i * 8 * KP + k0),
                (__attribute__((address_space(3))) void*)(alds + i * 8 * 64), 16, 0, 0);
            __builtin_amdgcn_global_load_lds(
                (const __attribute__((address_space(1))) void*)(bgbase + (size_t)i * 8 * KP + k0),
                (__attribute__((address_space(3))) void*)(blds + i * 8 * 64), 16, 0, 0);
        }
        __syncthreads();
#pragma unroll
        for (int kk = 0; kk < 2; ++kk) {
            bf16x8 a0 = As8[aoff + kk * 4 + 0 * 128];
            bf16x8 a1 = As8[aoff + kk * 4 + 1 * 128];
            bf16x8 a2 = As8[aoff + kk * 4 + 2 * 128];
            bf16x8 a3 = As8[aoff + kk * 4 + 3 * 128];
            bf16x8 b0 = Bs8[boff + kk * 4 + 0 * 128];
            bf16x8 b1 = Bs8[boff + kk * 4 + 1 * 128];
            bf16x8 b2 = Bs8[boff + kk * 4 + 2 * 128];
            bf16x8 b3 = Bs8[boff + kk * 4 + 3 * 128];
            acc[0][0] = __builtin_amdgcn_mfma_f32_16x16x32_bf16(a0, b0, acc[0][0], 0, 0, 0);
            acc[0][1] = __builtin_amdgcn_mfma_f32_16x16x32_bf16(a0, b1, acc[0][1], 0, 0, 0);
            acc[0][2] = __builtin_amdgcn_mfma_f32_16x16x32_bf16(a0, b2, acc[0][2], 0, 0, 0);
            acc[0][3] = __builtin_amdgcn_mfma_f32_16x16x32_bf16(a0, b3, acc[0][3], 0, 0, 0);
            acc[1][0] = __builtin_amdgcn_mfma_f32_16x16x32_bf16(a1, b0, acc[1][0], 0, 0, 0);
            acc[1][1] = __builtin_amdgcn_mfma_f32_16x16x32_bf16(a1, b1, acc[1][1], 0, 0, 0);
            acc[1][2] = __builtin_amdgcn_mfma_f32_16x16x32_bf16(a1, b2, acc[1][2], 0, 0, 0);
            acc[1][3] = __builtin_amdgcn_mfma_f32_16x16x32_bf16(a1, b3, acc[1][3], 0, 0, 0);
            acc[2][0] = __builtin_amdgcn_mfma_f32_16x16x32_bf16(a2, b0, acc[2][0], 0, 0, 0);
            acc[2][1] = __builtin_amdgcn_mfma_f32_16x16x32_bf16(a2, b1, acc[2][1], 0, 0, 0);
            acc[2][2] = __builtin_amdgcn_mfma_f32_16x16x32_bf16(a2, b2, acc[2][2], 0, 0, 0);
            acc[2][3] = __builtin_amdgcn_mfma_f32_16x16x32_bf16(a2, b3, acc[2][3], 0, 0, 0);
            acc[3][0] = __builtin_amdgcn_mfma_f32_16x16x32_bf16(a3, b0, acc[3][0], 0, 0, 0);
            acc[3][1] = __builtin_amdgcn_mfma_f32_16x16x32_bf16(a3, b1, acc[3][1], 0, 0, 0);
            acc[3][2] = __builtin_amdgcn_mfma_f32_16x16x32_bf16(a3, b2, acc[3][2], 0, 0, 0);
            acc[3][3] = __builtin_amdgcn_mfma_f32_16x16x32_bf16(a3, b3, acc[3][3], 0, 0, 0);
        }
        __syncthreads();
    }

    // C/D layout (m89-verified): col = lane&15, row = (lane>>4)*4 + reg
    const int mbase = bm * 128 + wr * 64 + fq * 4;
    const int nbase = bn * 128 + wc * 64 + fr;
#pragma unroll
    for (int i = 0; i < 4; ++i)
#pragma unroll
        for (int j = 0; j < 4; ++j)
#pragma unroll
            for (int r = 0; r < 4; ++r)
                Z[(size_t)(mbase + i * 16 + r) * HDIM + nbase + j * 16] = acc[i][j][r];
}

// ---------- Layer-1 approx IF recurrence + near-threshold flagging ----------
__global__ __launch_bounds__(256) void k_layer1_flag(const float* __restrict__ Z,
                                                     float* __restrict__ v1s,
                                                     uint64_t* __restrict__ S1,
                                                     uint64_t* __restrict__ flags,
                                                     int tbase, int first) {
    const size_t i = (size_t)blockIdx.x * 256 + threadIdx.x;
    float v = first ? 0.0f : v1s[i];
    const int lane = threadIdx.x & 63;
    const size_t word = i >> 6;
    uint64_t nearAcc = 0;
    for (int t = 0; t < TC; ++t) {
        v += Z[(size_t)t * BH + i];
        bool s    = (v >= 1.0f);
        bool near = (fabsf(v - 1.0f) < DELTA);
        unsigned long long sm = __ballot(s);
        nearAcc |= (uint64_t)__ballot(near);
        if (lane == 0) S1[(size_t)(tbase + t) * WORDS_PER_T + word] = sm;
        if (s) v = 0.0f;
    }
    if (lane == 0) flags[word] = first ? nearAcc : (flags[word] | nearAcc);
    v1s[i] = v;
}

// ---------- Exact fixup: recompute flagged (b,h) chains bitwise ----------
// Block per b. x staged in LDS 16 timesteps at a time; each flagged-h thread
// makes ONE ascending-k pass over its W1 row (float4), updating 16 independent
// z[t] accumulators per k (16-way ILP; each z[t] chain is ascending-k fma ->
// bitwise identical to the reference). v carried across the two half-passes.
__global__ __launch_bounds__(256) void k_fixup(const float* __restrict__ x,
                                               const float* __restrict__ W1,
                                               const uint64_t* __restrict__ flags,
                                               uint64_t* __restrict__ S1) {
    __shared__ float xs[16][788];   // [t][k], rows 16B-aligned; 50.4 KB
    __shared__ int   list[FIXLIST];
    __shared__ int   cnt;
    const int b   = blockIdx.x;
    const int tid = threadIdx.x;
    if (tid == 0) cnt = 0;
    __syncthreads();
    if (tid < 64) {
        uint64_t w = flags[b * 64 + tid];
        while (w) {
            int bit = __builtin_ctzll(w);
            w &= w - 1;
            int p = atomicAdd(&cnt, 1);
            if (p < FIXLIST) list[p] = tid * 64 + bit;
        }
    }
    __syncthreads();
    const int n = min(cnt, FIXLIST);
    if (n == 0) return;

    for (int j0 = 0; j0 < n; j0 += 256) {
        const int j = j0 + tid;
        const int h = (j < n) ? list[j] : -1;
        const float* wrow = W1 + (size_t)(h >= 0 ? h : 0) * INDIM;
        float v = 0.0f;
        for (int half = 0; half < 2; ++half) {
            __syncthreads();   // previous pass done reading xs
            for (int idx = tid; idx < 16 * 196; idx += 256) {
                int t  = idx / 196;
                int kq = (idx % 196) * 4;
                float4 vx = *(const float4*)(x + ((size_t)(half * 16 + t) * BATCH + b) * INDIM + kq);
                *(float4*)&xs[t][kq] = vx;
            }
            __syncthreads();
            if (h >= 0) {
                float z[16];
#pragma unroll
                for (int t = 0; t < 16; ++t) z[t] = 0.0f;
                for (int kq = 0; kq < INDIM; kq += 4) {
                    float4 w4 = *(const float4*)(wrow + kq);
#pragma unroll
                    for (int t = 0; t < 16; ++t) {
                        float4 xv = *(const float4*)&xs[t][kq];   // wave-broadcast reads
                        z[t] = fmaf(xv.x, w4.x, z[t]);
                        z[t] = fmaf(xv.y, w4.y, z[t]);
                        z[t] = fmaf(xv.z, w4.z, z[t]);
                        z[t] = fmaf(xv.w, w4.w, z[t]);
                    }
                }
#pragma unroll
                for (int t = 0; t < 16; ++t) {
                    v += z[t];
                    bool s = (v >= 1.0f);
                    unsigned long long* wp = (unsigned long long*)
                        &S1[(size_t)(half * 16 + t) * WORDS_PER_T + (size_t)b * 64 + (h >> 6)];
                    unsigned long long m = 1ull << (h & 63);
                    if (s) { atomicOr(wp, m); v = 0.0f; }
                    else   { atomicAnd(wp, ~m); }
                }
            }
        }
    }
}

// ---------- Layer-2 partial sums from spike bitmask ----------
__global__ __launch_bounds__(256) void k_layer2_partial(const uint64_t* __restrict__ S1,
                                                        const float* __restrict__ W2T,
                                                        float* __restrict__ part,
                                                        int rowsTotal) {
    __shared__ float w[1024][10];   // 40 KB
    const int hs = blockIdx.y;
    for (int i = threadIdx.x; i < 1024 * 10; i += 256)
        w[i / 10][i % 10] = W2T[hs * 1024 * 10 + i];
    __syncthreads();

    const int row = blockIdx.x * 256 + threadIdx.x;
    const uint64_t* wp = S1 + (size_t)row * 64 + hs * 16;
    float acc[10] = {};
    for (int wi = 0; wi < 16; ++wi) {
        uint64_t m = wp[wi];
        while (m) {
            int bit = __builtin_ctzll(m);
            m &= m - 1;
            int hl = wi * 64 + bit;
#pragma unroll
            for (int o = 0; o < 10; ++o) acc[o] += w[hl][o];
        }
    }
    float* p = part + ((size_t)hs * rowsTotal + row) * 10;
#pragma unroll
    for (int o = 0; o < 10; ++o) p[o] = acc[o];
}

// ---------- Layer-2 IF recurrence + spike record ----------
__global__ __launch_bounds__(256) void k_layer2_rec(const float* __restrict__ part,
                                                    float* __restrict__ out) {
    const int i = blockIdx.x * 256 + threadIdx.x;
    if (i >= BATCH * OUTDIM) return;
    float v = 0.0f, rec = 0.0f;
    const int rowsTotal = T_TOTAL * BATCH;
    const int b = i / OUTDIM, o = i % OUTDIM;
    for (int t = 0; t < T_TOTAL; ++t) {
        const int r = t * BATCH + b;
        float sig = 0.0f;
#pragma unroll
        for (int hs = 0; hs < 4; ++hs)
            sig += part[((size_t)hs * rowsTotal + r) * 10 + o];
        v += sig;
        bool s = (v >= 1.0f);
        rec += s ? 1.0f : 0.0f;
        if (s) v = 0.0f;
    }
    out[i] = rec;
}

// ---------- launch ----------
extern "C" void kernel_launch(void* const* d_in, const int* in_sizes, int n_in,
                              void* d_out, int out_size, void* d_ws, size_t ws_size,
                              hipStream_t stream) {
    (void)in_sizes; (void)n_in; (void)out_size; (void)ws_size;
    const float* x  = (const float*)d_in[0];   // [32][1024][784]
    const float* W1 = (const float*)d_in[1];   // [4096][784]
    const float* W2 = (const float*)d_in[2];   // [10][4096]
    float* out = (float*)d_out;                // [1024][10]

    // ws layout (total ~230 MB)
    char* p = (char*)d_ws;
    float*    W2T   = (float*)p;    p += (size_t)HDIM * OUTDIM * 4;        // 160 KB
    float*    v1s   = (float*)p;    p += (size_t)BH * 4;                   // 16.8 MB
    ushort*   Bp    = (ushort*)p;   p += (size_t)HDIM * KP * 2;            // 19.4 MB
    ushort*   Ap    = (ushort*)p;   p += (size_t)MC * KP * 2;              // 38.8 MB
    float*    Z     = (float*)p;    p += (size_t)TC * BH * 4;              // 134.2 MB
    uint64_t* S1    = (uint64_t*)p; p += (size_t)T_TOTAL * WORDS_PER_T * 8;// 16.8 MB
    uint64_t* flags = (uint64_t*)p; p += (size_t)WORDS_PER_T * 8;          // 0.5 MB
    float*    part  = (float*)p;                                           // 5.2 MB

    k_transpose_w2<<<(HDIM * OUTDIM + 255) / 256, 256, 0, stream>>>(W2, W2T);
    k_split3<<<(HDIM * 400 + 255) / 256, 256, 0, stream>>>(W1, Bp, HDIM, 0);

    const int nch = T_TOTAL / TC;   // 4
    for (int c = 0; c < nch; ++c) {
        const float* xc = x + (size_t)c * MC * INDIM;
        k_split3<<<(MC * 400 + 255) / 256, 256, 0, stream>>>(xc, Ap, MC, 1);
        k_gemm_bf16<<<(MC / 128) * 32, 256, 0, stream>>>(Ap, Bp, Z);
        k_layer1_flag<<<BH / 256, 256, 0, stream>>>(Z, v1s, S1, flags, c * TC, c == 0);
    }
    k_fixup<<<BATCH, 256, 0, stream>>>(x, W1, flags, S1);
    k_layer2_partial<<<dim3(T_TOTAL * BATCH / 256, 4), 256, 0, stream>>>(
        S1, W2T, part, T_TOTAL * BATCH);
    k_layer2_rec<<<(BATCH * OUTDIM + 255) / 256, 256, 0, stream>>>(part, out);
}